// Round 5
// baseline (1064.450 us; speedup 1.0000x reference)
//
#include <hip/hip_runtime.h>
#include <hip/hip_bf16.h>

// Fused window cross-attention for MI355X (gfx950). fp32 inputs, fp32 outputs.
// One workgroup (1024 thr = 16 waves) per 8x8 window. All intermediates in LDS (bf16).
// Wave (q,th): q = 64-col group / head, th = 16-token quarter.
//
// Phases (barrier-separated):
//  P0: stage X_a, X_b  (global fp32 loads, cvt->bf16, transposed writes, swizzled LDS)
//  P1: Q = Xa*Wq^T + bq -> QQ ; K = Xb*Wk^T + bk -> KK   (W frags: fp32 L2 loads + cvt)
//  P2: S = Q_h K_h^T, scaled softmax -> P (XA region, bf16)
//  P3: V^T = Wv*Xb^T + bv -> QQ region ; copy P -> global attn (fp32, coalesced)
//  P4: O = P*V -> KK region
//  P5: Out^T = Wo*O^T + bo -> global out (fp32, channel-major)

typedef __bf16 bf16x8 __attribute__((ext_vector_type(8)));
typedef float f32x4 __attribute__((ext_vector_type(4)));
typedef unsigned short u16;
typedef unsigned short u16x8 __attribute__((ext_vector_type(8)));

#define MFMA16(A, B, C) __builtin_amdgcn_mfma_f32_16x16x32_bf16((A), (B), (C), 0, 0, 0)

// XOR swizzle on 16B quads within each 128B sub-block; g(row)=(row&7)^(row>>3)
__device__ __forceinline__ int swzA(int t, int byteInRow) {        // rows of 512B ([64][256] bf16)
    return (t << 9) + (byteInRow ^ ((((t & 7) ^ (t >> 3)) & 7) << 4));
}
__device__ __forceinline__ int swzB(int r, int byteInRow) {        // rows of 128B ([*][64] bf16)
    return (r << 7) + (byteInRow ^ ((((r & 7) ^ (r >> 3)) & 7) << 4));
}

// 8 consecutive fp32 -> bf16x8 fragment (two 16B loads, L2-resident weights)
__device__ __forceinline__ bf16x8 loadW8(const float* __restrict__ p) {
    f32x4 a = *(const f32x4*)p;
    f32x4 b = *(const f32x4*)(p + 4);
    bf16x8 r;
    r[0] = (__bf16)a[0]; r[1] = (__bf16)a[1]; r[2] = (__bf16)a[2]; r[3] = (__bf16)a[3];
    r[4] = (__bf16)b[0]; r[5] = (__bf16)b[1]; r[6] = (__bf16)b[2]; r[7] = (__bf16)b[3];
    return r;
}

__global__ __launch_bounds__(1024) void wca_fused(
    const float* __restrict__ fa, const float* __restrict__ fb,
    const float* __restrict__ Wq, const float* __restrict__ bq,
    const float* __restrict__ Wk, const float* __restrict__ bk,
    const float* __restrict__ Wv, const float* __restrict__ bv,
    const float* __restrict__ Wo, const float* __restrict__ bo,
    float* __restrict__ outg, float* __restrict__ attng)
{
    __shared__ __attribute__((aligned(16))) char S[131072];
    char* const XA = S;              // X_a [64][256]; later P[4][64][64]
    char* const XB = S + 32768;      // X_b [64][256]
    char* const QQ = S + 65536;      // Q   [64][256]; later V^T [256][64]
    char* const KK = S + 98304;      // K   [64][256]; later O   [64][256]

    const int tid  = threadIdx.x;
    const int l    = tid & 63;
    const int wid  = tid >> 6;      // wave 0..15
    const int lrow = l & 15;
    const int kg   = l >> 4;
    const int q    = wid & 3;       // 64-wide output col group / head id
    const int th   = wid >> 2;      // 16-token quarter (0..3)

    // XCD-bijective swizzle: XCD k (= wgid%8) owns batch k; wx fastest within.
    const int wgid = blockIdx.x;
    const int win  = ((wgid & 7) << 8) | (wgid >> 3);
    const int b    = win >> 8;
    const int wy   = (win >> 4) & 15;
    const int wx   = win & 15;
    const int ybase = wy << 3, xbase = wx << 3;

    // ---------------- P0: stage X_a, X_b (fp32 -> bf16) ----------------
    {
        #pragma unroll
        for (int f = 0; f < 2; ++f) {
            const float* src = f ? fb : fa;
            char* dst = f ? XB : XA;
            #pragma unroll
            for (int it = 0; it < 2; ++it) {
                int idx = (it << 10) + tid;         // 0..2047 = (c, ty)
                int c  = idx >> 3;
                int ty = idx & 7;
                const float* gp = src + ((((size_t)b * 256 + c) * 128 + ybase + ty) * 128 + xbase);
                f32x4 v0 = *(const f32x4*)gp;       // 8 pixels (tx 0..7), 32B
                f32x4 v1 = *(const f32x4*)(gp + 4);
                #pragma unroll
                for (int tx = 0; tx < 4; ++tx) {
                    int t0 = (ty << 3) + tx;
                    int t1 = (ty << 3) + 4 + tx;
                    *(__bf16*)(dst + swzA(t0, c << 1)) = (__bf16)v0[tx];
                    *(__bf16*)(dst + swzA(t1, c << 1)) = (__bf16)v1[tx];
                }
            }
        }
    }
    __syncthreads();

    // ---------------- P1: Q and K projections ----------------
    {
        #pragma unroll
        for (int pp = 0; pp < 2; ++pp) {
            const float* W    = pp ? Wk : Wq;
            const float* bias = pp ? bk : bq;
            const char* Xs  = pp ? XB : XA;
            char* dstR      = pp ? KK : QQ;
            f32x4 acc[4] = {};
            #pragma unroll
            for (int kk = 0; kk < 8; ++kk) {
                int c0 = (kk << 5) + (kg << 3);
                bf16x8 a0 = *(const bf16x8*)(Xs + swzA((th << 4) + lrow, c0 << 1));
                #pragma unroll
                for (int nt = 0; nt < 4; ++nt) {
                    bf16x8 bb = loadW8(W + ((q << 6) + (nt << 4) + lrow) * 256 + c0);
                    acc[nt] = MFMA16(a0, bb, acc[nt]);
                }
            }
            #pragma unroll
            for (int nt = 0; nt < 4; ++nt) {
                int co = (q << 6) + (nt << 4) + lrow;
                float bi = bias[co];
                #pragma unroll
                for (int r = 0; r < 4; ++r) {
                    int t = (th << 4) + (kg << 2) + r;
                    *(__bf16*)(dstR + swzA(t, co << 1)) = (__bf16)(acc[nt][r] + bi);
                }
            }
        }
    }
    __syncthreads();

    // ---------------- P2: S = Q_h K_h^T, softmax -> P ----------------
    {
        const int h = q;
        f32x4 s[4] = {};
        #pragma unroll
        for (int kk = 0; kk < 2; ++kk) {
            int c0 = (h << 6) + (kk << 5) + (kg << 3);
            bf16x8 a0 = *(const bf16x8*)(QQ + swzA((th << 4) + lrow, c0 << 1));
            #pragma unroll
            for (int nt = 0; nt < 4; ++nt) {
                bf16x8 kb = *(const bf16x8*)(KK + swzA((nt << 4) + lrow, c0 << 1));
                s[nt] = MFMA16(a0, kb, s[nt]);
            }
        }
        const float CS = 0.125f * 1.44269504f;   // scale * log2(e)
        #pragma unroll
        for (int r = 0; r < 4; ++r) {
            float mx = fmaxf(fmaxf(s[0][r], s[1][r]), fmaxf(s[2][r], s[3][r]));
            mx = fmaxf(mx, __shfl_xor(mx, 1));
            mx = fmaxf(mx, __shfl_xor(mx, 2));
            mx = fmaxf(mx, __shfl_xor(mx, 4));
            mx = fmaxf(mx, __shfl_xor(mx, 8));
            float p0 = exp2f((s[0][r] - mx) * CS);
            float p1 = exp2f((s[1][r] - mx) * CS);
            float p2 = exp2f((s[2][r] - mx) * CS);
            float p3 = exp2f((s[3][r] - mx) * CS);
            float sm = (p0 + p1) + (p2 + p3);
            sm += __shfl_xor(sm, 1);
            sm += __shfl_xor(sm, 2);
            sm += __shfl_xor(sm, 4);
            sm += __shfl_xor(sm, 8);
            float inv = 1.0f / sm;
            int i = (th << 4) + (kg << 2) + r;
            char* pb = XA + (h << 13);
            *(__bf16*)(pb + swzB(i, ((0 << 4) + lrow) << 1)) = (__bf16)(p0 * inv);
            *(__bf16*)(pb + swzB(i, ((1 << 4) + lrow) << 1)) = (__bf16)(p1 * inv);
            *(__bf16*)(pb + swzB(i, ((2 << 4) + lrow) << 1)) = (__bf16)(p2 * inv);
            *(__bf16*)(pb + swzB(i, ((3 << 4) + lrow) << 1)) = (__bf16)(p3 * inv);
        }
    }
    __syncthreads();

    // ---------------- P3: V^T = Wv * Xb^T (into QQ region) + attn copy (fp32) ----------------
    {
        f32x4 acc[4] = {};
        #pragma unroll
        for (int kk = 0; kk < 8; ++kk) {
            int c0 = (kk << 5) + (kg << 3);
            bf16x8 bx = *(const bf16x8*)(XB + swzA((th << 4) + lrow, c0 << 1));
            #pragma unroll
            for (int mt = 0; mt < 4; ++mt) {
                bf16x8 aw = loadW8(Wv + ((q << 6) + (mt << 4) + lrow) * 256 + c0);
                acc[mt] = MFMA16(aw, bx, acc[mt]);
            }
        }
        #pragma unroll
        for (int mt = 0; mt < 4; ++mt) {
            #pragma unroll
            for (int r = 0; r < 4; ++r) {
                int vc = (q << 6) + (mt << 4) + (kg << 2) + r;   // channel row of V^T
                float bi = bv[vc];
                int t = (th << 4) + lrow;
                *(__bf16*)(QQ + swzB(vc, t << 1)) = (__bf16)(acc[mt][r] + bi);
            }
        }
        // attn: P (LDS bf16) -> global fp32, 32B per lane coalesced
        #pragma unroll
        for (int it = 0; it < 2; ++it) {
            int idx = (it << 10) + tid;                // 0..2047
            int h2 = idx >> 9;
            int i2 = (idx >> 3) & 63;
            int jb = (idx & 7) << 3;
            u16x8 v = *(const u16x8*)(XA + (h2 << 13) + swzB(i2, jb << 1));
            float* dp = attng + ((((size_t)(win << 2) + h2) << 6) + i2) * 64 + jb;
            f32x4 o0, o1;
            #pragma unroll
            for (int e = 0; e < 4; ++e) {
                union { unsigned u; float f; } c0; c0.u = (unsigned)v[e] << 16;
                union { unsigned u; float f; } c1; c1.u = (unsigned)v[4 + e] << 16;
                o0[e] = c0.f; o1[e] = c1.f;
            }
            *(f32x4*)dp = o0;
            *(f32x4*)(dp + 4) = o1;
        }
    }
    __syncthreads();

    // ---------------- P4: O = P * V (into KK region) ----------------
    {
        const int h = q;
        f32x4 o[4] = {};
        #pragma unroll
        for (int kk = 0; kk < 2; ++kk) {
            int j0 = (kk << 5) + (kg << 3);
            bf16x8 a0 = *(const bf16x8*)(XA + (h << 13) + swzB((th << 4) + lrow, j0 << 1));
            #pragma unroll
            for (int dt = 0; dt < 4; ++dt) {
                bf16x8 vb = *(const bf16x8*)(QQ + swzB((h << 6) + (dt << 4) + lrow, j0 << 1));
                o[dt] = MFMA16(a0, vb, o[dt]);
            }
        }
        #pragma unroll
        for (int dt = 0; dt < 4; ++dt) {
            #pragma unroll
            for (int r = 0; r < 4; ++r) {
                int t = (th << 4) + (kg << 2) + r;
                int c = (h << 6) + (dt << 4) + lrow;
                *(__bf16*)(KK + swzA(t, c << 1)) = (__bf16)o[dt][r];
            }
        }
    }
    __syncthreads();

    // ---------------- P5: Out^T = Wo * O^T + bo -> global (fp32) ----------------
    {
        f32x4 acc[4] = {};
        #pragma unroll
        for (int kk = 0; kk < 8; ++kk) {
            int k0 = (kk << 5) + (kg << 3);
            bf16x8 b0 = *(const bf16x8*)(KK + swzA((th << 4) + lrow, k0 << 1));
            #pragma unroll
            for (int mt = 0; mt < 4; ++mt) {
                bf16x8 aw = loadW8(Wo + ((q << 6) + (mt << 4) + lrow) * 256 + k0);
                acc[mt] = MFMA16(aw, b0, acc[mt]);
            }
        }
        #pragma unroll
        for (int mt = 0; mt < 4; ++mt) {
            #pragma unroll
            for (int r = 0; r < 4; ++r) {
                int c = (q << 6) + (mt << 4) + (kg << 2) + r;
                float bi = bo[c];
                int t = (th << 4) + lrow;
                int y = ybase + (t >> 3);
                int x = xbase + (t & 7);
                size_t off = (((size_t)b * 256 + c) * 128 + y) * 128 + x;
                outg[off] = acc[mt][r] + bi;
            }
        }
    }
}

extern "C" void kernel_launch(void* const* d_in, const int* in_sizes, int n_in,
                              void* d_out, int out_size, void* d_ws, size_t ws_size,
                              hipStream_t stream) {
    (void)in_sizes; (void)n_in; (void)d_ws; (void)ws_size; (void)out_size;
    const float* fa = (const float*)d_in[0];
    const float* fb = (const float*)d_in[1];
    const float* Wq = (const float*)d_in[2];
    const float* bq = (const float*)d_in[3];
    const float* Wk = (const float*)d_in[4];
    const float* bk = (const float*)d_in[5];
    const float* Wv = (const float*)d_in[6];
    const float* bv = (const float*)d_in[7];
    const float* Wo = (const float*)d_in[8];
    const float* bo = (const float*)d_in[9];
    float* outg  = (float*)d_out;
    float* attng = outg + (size_t)8 * 256 * 128 * 128;   // out first, then attn (fp32)
    wca_fused<<<dim3(2048), dim3(1024), 0, stream>>>(
        fa, fb, Wq, bq, Wk, bk, Wv, bv, Wo, bo, outg, attng);
}

// Round 6
// 310.372 us; speedup vs baseline: 3.4296x; 3.4296x over previous
//
#include <hip/hip_runtime.h>
#include <hip/hip_bf16.h>

// Fused window cross-attention for MI355X (gfx950). fp32 inputs, fp32 outputs.
// Round 6: round-4 structure (512 thr / 8 waves per 8x8 window, 128KB LDS) +
// weight pre-pack kernel: all 4 projection matrices converted fp32->bf16 into
// MFMA-fragment order in d_ws, so the main kernel's weight loads are single
// coalesced 16B/lane global loads (no gather, no cvt).
//
// Packed layout (per matrix, 65536 bf16 = 128KB):
//   frag_id = ((q*8 + kk)*4 + t16)         (q: 64-row group, kk: 32-col block, t16: 16-row tile)
//   element  = pk[frag_id*512 + l*8 + e] = W[(q*64 + t16*16 + (l&15))*256 + kk*32 + (l>>4)*8 + e]

typedef __bf16 bf16x8 __attribute__((ext_vector_type(8)));
typedef float f32x4 __attribute__((ext_vector_type(4)));
typedef unsigned short u16;
typedef unsigned short u16x8 __attribute__((ext_vector_type(8)));

#define MFMA16(A, B, C) __builtin_amdgcn_mfma_f32_16x16x32_bf16((A), (B), (C), 0, 0, 0)

// XOR swizzle on 16B quads within each 128B sub-block; g(row)=(row&7)^(row>>3)
__device__ __forceinline__ int swzA(int t, int byteInRow) {        // rows of 512B ([64][256] bf16)
    return (t << 9) + (byteInRow ^ ((((t & 7) ^ (t >> 3)) & 7) << 4));
}
__device__ __forceinline__ int swzB(int r, int byteInRow) {        // rows of 128B ([*][64] bf16)
    return (r << 7) + (byteInRow ^ ((((r & 7) ^ (r >> 3)) & 7) << 4));
}

// ---------------- prep: pack weights into fragment order ----------------
__global__ __launch_bounds__(256) void pack_weights(
    const float* __restrict__ Wq, const float* __restrict__ Wk,
    const float* __restrict__ Wv, const float* __restrict__ Wo,
    __bf16* __restrict__ pk)
{
    int gid = blockIdx.x * 256 + threadIdx.x;   // 0..32767 (4 matrices x 8192 frags)
    int m = gid >> 13;
    int f = gid & 8191;
    const float* W = (m == 0) ? Wq : (m == 1) ? Wk : (m == 2) ? Wv : Wo;
    int q  = f >> 11;
    int kk = (f >> 8) & 7;
    int t16 = (f >> 6) & 3;
    int l  = f & 63;
    int row = (q << 6) + (t16 << 4) + (l & 15);
    int col = (kk << 5) + ((l >> 4) << 3);
    const float* s = W + row * 256 + col;
    f32x4 a = *(const f32x4*)s;
    f32x4 b = *(const f32x4*)(s + 4);
    bf16x8 r;
    r[0] = (__bf16)a[0]; r[1] = (__bf16)a[1]; r[2] = (__bf16)a[2]; r[3] = (__bf16)a[3];
    r[4] = (__bf16)b[0]; r[5] = (__bf16)b[1]; r[6] = (__bf16)b[2]; r[7] = (__bf16)b[3];
    *(bf16x8*)(pk + (size_t)gid * 8) = r;
}

// packed-weight fragment load: fully coalesced, 16B per lane
__device__ __forceinline__ bf16x8 loadWP(const __bf16* __restrict__ pk,
                                         int q, int kk, int t16, int l) {
    return *(const bf16x8*)(pk + ((((q << 3) + kk) << 2) + t16) * 512 + (l << 3));
}

__global__ __launch_bounds__(512) void wca_fused(
    const float* __restrict__ fa, const float* __restrict__ fb,
    const __bf16* __restrict__ WPq, const float* __restrict__ bq,
    const __bf16* __restrict__ WPk, const float* __restrict__ bk,
    const __bf16* __restrict__ WPv, const float* __restrict__ bv,
    const __bf16* __restrict__ WPo, const float* __restrict__ bo,
    float* __restrict__ outg, float* __restrict__ attng)
{
    __shared__ __attribute__((aligned(16))) char S[131072];
    char* const XA = S;              // X_a [64][256]; later P[4][64][64]
    char* const XB = S + 32768;      // X_b [64][256]
    char* const QQ = S + 65536;      // Q   [64][256]; later V^T [256][64]
    char* const KK = S + 98304;      // K   [64][256]; later O   [64][256]

    const int tid  = threadIdx.x;
    const int l    = tid & 63;
    const int wid  = tid >> 6;      // wave 0..7
    const int lrow = l & 15;
    const int kg   = l >> 4;
    const int q    = wid & 3;       // 64-wide output chunk / head id
    const int th   = wid >> 2;      // token half (0/1)

    // XCD-bijective swizzle: XCD k (= wgid%8) owns batch k; wx fastest within.
    const int wgid = blockIdx.x;
    const int win  = ((wgid & 7) << 8) | (wgid >> 3);
    const int b    = win >> 8;
    const int wy   = (win >> 4) & 15;
    const int wx   = win & 15;
    const int ybase = wy << 3, xbase = wx << 3;

    // ---------------- P0: stage X_a, X_b (fp32 -> bf16) ----------------
    {
        #pragma unroll
        for (int f = 0; f < 2; ++f) {
            const float* src = f ? fb : fa;
            char* dst = f ? XB : XA;
            #pragma unroll
            for (int it = 0; it < 4; ++it) {
                int idx = (it << 9) + tid;          // 0..2047 = (c, ty)
                int c  = idx >> 3;
                int ty = idx & 7;
                const float* gp = src + ((((size_t)b * 256 + c) * 128 + ybase + ty) * 128 + xbase);
                f32x4 v0 = *(const f32x4*)gp;       // 8 pixels (tx 0..7), 32B
                f32x4 v1 = *(const f32x4*)(gp + 4);
                #pragma unroll
                for (int tx = 0; tx < 4; ++tx) {
                    int t0 = (ty << 3) + tx;
                    int t1 = (ty << 3) + 4 + tx;
                    *(__bf16*)(dst + swzA(t0, c << 1)) = (__bf16)v0[tx];
                    *(__bf16*)(dst + swzA(t1, c << 1)) = (__bf16)v1[tx];
                }
            }
        }
    }
    __syncthreads();

    // ---------------- P1: Q and K projections ----------------
    {
        #pragma unroll
        for (int pp = 0; pp < 2; ++pp) {
            const __bf16* WP  = pp ? WPk : WPq;
            const float* bias = pp ? bk : bq;
            const char* Xs  = pp ? XB : XA;
            char* dstR      = pp ? KK : QQ;
            f32x4 acc[2][4] = {};
            #pragma unroll
            for (int kk = 0; kk < 8; ++kk) {
                int c0 = (kk << 5) + (kg << 3);
                bf16x8 a0 = *(const bf16x8*)(Xs + swzA((th << 5) + lrow,      c0 << 1));
                bf16x8 a1 = *(const bf16x8*)(Xs + swzA((th << 5) + 16 + lrow, c0 << 1));
                #pragma unroll
                for (int nt = 0; nt < 4; ++nt) {
                    bf16x8 bb = loadWP(WP, q, kk, nt, l);
                    acc[0][nt] = MFMA16(a0, bb, acc[0][nt]);
                    acc[1][nt] = MFMA16(a1, bb, acc[1][nt]);
                }
            }
            #pragma unroll
            for (int mt = 0; mt < 2; ++mt) {
                #pragma unroll
                for (int nt = 0; nt < 4; ++nt) {
                    int co = (q << 6) + (nt << 4) + lrow;
                    float bi = bias[co];
                    #pragma unroll
                    for (int r = 0; r < 4; ++r) {
                        int t = (th << 5) + (mt << 4) + (kg << 2) + r;
                        *(__bf16*)(dstR + swzA(t, co << 1)) = (__bf16)(acc[mt][nt][r] + bi);
                    }
                }
            }
        }
    }
    __syncthreads();

    // ---------------- P2: S = Q_h K_h^T, softmax -> P ----------------
    {
        const int h = q;
        f32x4 s[2][4] = {};
        #pragma unroll
        for (int kk = 0; kk < 2; ++kk) {
            int c0 = (h << 6) + (kk << 5) + (kg << 3);
            bf16x8 a0 = *(const bf16x8*)(QQ + swzA((th << 5) + lrow,      c0 << 1));
            bf16x8 a1 = *(const bf16x8*)(QQ + swzA((th << 5) + 16 + lrow, c0 << 1));
            #pragma unroll
            for (int nt = 0; nt < 4; ++nt) {
                bf16x8 kb = *(const bf16x8*)(KK + swzA((nt << 4) + lrow, c0 << 1));
                s[0][nt] = MFMA16(a0, kb, s[0][nt]);
                s[1][nt] = MFMA16(a1, kb, s[1][nt]);
            }
        }
        const float CS = 0.125f * 1.44269504f;   // scale * log2(e)
        #pragma unroll
        for (int mt = 0; mt < 2; ++mt) {
            #pragma unroll
            for (int r = 0; r < 4; ++r) {
                float mx = fmaxf(fmaxf(s[mt][0][r], s[mt][1][r]),
                                 fmaxf(s[mt][2][r], s[mt][3][r]));
                mx = fmaxf(mx, __shfl_xor(mx, 1));
                mx = fmaxf(mx, __shfl_xor(mx, 2));
                mx = fmaxf(mx, __shfl_xor(mx, 4));
                mx = fmaxf(mx, __shfl_xor(mx, 8));
                float p0 = exp2f((s[mt][0][r] - mx) * CS);
                float p1 = exp2f((s[mt][1][r] - mx) * CS);
                float p2 = exp2f((s[mt][2][r] - mx) * CS);
                float p3 = exp2f((s[mt][3][r] - mx) * CS);
                float sm = (p0 + p1) + (p2 + p3);
                sm += __shfl_xor(sm, 1);
                sm += __shfl_xor(sm, 2);
                sm += __shfl_xor(sm, 4);
                sm += __shfl_xor(sm, 8);
                float inv = 1.0f / sm;
                int i = (th << 5) + (mt << 4) + (kg << 2) + r;
                char* pb = XA + (h << 13);
                *(__bf16*)(pb + swzB(i, ((0 << 4) + lrow) << 1)) = (__bf16)(p0 * inv);
                *(__bf16*)(pb + swzB(i, ((1 << 4) + lrow) << 1)) = (__bf16)(p1 * inv);
                *(__bf16*)(pb + swzB(i, ((2 << 4) + lrow) << 1)) = (__bf16)(p2 * inv);
                *(__bf16*)(pb + swzB(i, ((3 << 4) + lrow) << 1)) = (__bf16)(p3 * inv);
            }
        }
    }
    __syncthreads();

    // ---------------- P3: V^T = Wv * Xb^T (into QQ region) + attn copy (fp32) ----------------
    {
        f32x4 acc[4][2] = {};
        #pragma unroll
        for (int kk = 0; kk < 8; ++kk) {
            int c0 = (kk << 5) + (kg << 3);
            bf16x8 bx0 = *(const bf16x8*)(XB + swzA((th << 5) + lrow,      c0 << 1));
            bf16x8 bx1 = *(const bf16x8*)(XB + swzA((th << 5) + 16 + lrow, c0 << 1));
            #pragma unroll
            for (int mt = 0; mt < 4; ++mt) {
                bf16x8 aw = loadWP(WPv, q, kk, mt, l);
                acc[mt][0] = MFMA16(aw, bx0, acc[mt][0]);
                acc[mt][1] = MFMA16(aw, bx1, acc[mt][1]);
            }
        }
        #pragma unroll
        for (int mt = 0; mt < 4; ++mt) {
            #pragma unroll
            for (int r = 0; r < 4; ++r) {
                int vc = (q << 6) + (mt << 4) + (kg << 2) + r;   // channel row of V^T
                float bi = bv[vc];
                #pragma unroll
                for (int nt = 0; nt < 2; ++nt) {
                    int t = (th << 5) + (nt << 4) + lrow;
                    *(__bf16*)(QQ + swzB(vc, t << 1)) = (__bf16)(acc[mt][nt][r] + bi);
                }
            }
        }
        // attn: P (LDS bf16) -> global fp32, 32B per lane coalesced
        #pragma unroll
        for (int it = 0; it < 4; ++it) {
            int idx = (it << 9) + tid;                 // 0..2047
            int h2 = idx >> 9;
            int i2 = (idx >> 3) & 63;
            int jb = (idx & 7) << 3;
            u16x8 v = *(const u16x8*)(XA + (h2 << 13) + swzB(i2, jb << 1));
            float* dp = attng + ((((size_t)(win << 2) + h2) << 6) + i2) * 64 + jb;
            f32x4 o0, o1;
            #pragma unroll
            for (int e = 0; e < 4; ++e) {
                union { unsigned u; float f; } c0; c0.u = (unsigned)v[e] << 16;
                union { unsigned u; float f; } c1; c1.u = (unsigned)v[4 + e] << 16;
                o0[e] = c0.f; o1[e] = c1.f;
            }
            *(f32x4*)dp = o0;
            *(f32x4*)(dp + 4) = o1;
        }
    }
    __syncthreads();

    // ---------------- P4: O = P * V (into KK region) ----------------
    {
        const int h = q;
        f32x4 o[2][4] = {};
        #pragma unroll
        for (int kk = 0; kk < 2; ++kk) {
            int j0 = (kk << 5) + (kg << 3);
            bf16x8 a0 = *(const bf16x8*)(XA + (h << 13) + swzB((th << 5) + lrow,      j0 << 1));
            bf16x8 a1 = *(const bf16x8*)(XA + (h << 13) + swzB((th << 5) + 16 + lrow, j0 << 1));
            #pragma unroll
            for (int dt = 0; dt < 4; ++dt) {
                bf16x8 vb = *(const bf16x8*)(QQ + swzB((h << 6) + (dt << 4) + lrow, j0 << 1));
                o[0][dt] = MFMA16(a0, vb, o[0][dt]);
                o[1][dt] = MFMA16(a1, vb, o[1][dt]);
            }
        }
        #pragma unroll
        for (int mt = 0; mt < 2; ++mt) {
            #pragma unroll
            for (int dt = 0; dt < 4; ++dt) {
                #pragma unroll
                for (int r = 0; r < 4; ++r) {
                    int t = (th << 5) + (mt << 4) + (kg << 2) + r;
                    int c = (h << 6) + (dt << 4) + lrow;
                    *(__bf16*)(KK + swzA(t, c << 1)) = (__bf16)o[mt][dt][r];
                }
            }
        }
    }
    __syncthreads();

    // ---------------- P5: Out^T = Wo * O^T + bo -> global (fp32) ----------------
    {
        f32x4 acc[4][2] = {};
        #pragma unroll
        for (int kk = 0; kk < 8; ++kk) {
            int k0 = (kk << 5) + (kg << 3);
            bf16x8 b0 = *(const bf16x8*)(KK + swzA((th << 5) + lrow,      k0 << 1));
            bf16x8 b1 = *(const bf16x8*)(KK + swzA((th << 5) + 16 + lrow, k0 << 1));
            #pragma unroll
            for (int mt = 0; mt < 4; ++mt) {
                bf16x8 aw = loadWP(WPo, q, kk, mt, l);
                acc[mt][0] = MFMA16(aw, b0, acc[mt][0]);
                acc[mt][1] = MFMA16(aw, b1, acc[mt][1]);
            }
        }
        #pragma unroll
        for (int mt = 0; mt < 4; ++mt) {
            #pragma unroll
            for (int r = 0; r < 4; ++r) {
                int c = (q << 6) + (mt << 4) + (kg << 2) + r;
                float bi = bo[c];
                #pragma unroll
                for (int nt = 0; nt < 2; ++nt) {
                    int t = (th << 5) + (nt << 4) + lrow;
                    int y = ybase + (t >> 3);
                    int x = xbase + (t & 7);
                    size_t off = (((size_t)b * 256 + c) * 128 + y) * 128 + x;
                    outg[off] = acc[mt][nt][r] + bi;
                }
            }
        }
    }
}

extern "C" void kernel_launch(void* const* d_in, const int* in_sizes, int n_in,
                              void* d_out, int out_size, void* d_ws, size_t ws_size,
                              hipStream_t stream) {
    (void)in_sizes; (void)n_in; (void)ws_size; (void)out_size;
    const float* fa = (const float*)d_in[0];
    const float* fb = (const float*)d_in[1];
    const float* Wq = (const float*)d_in[2];
    const float* bq = (const float*)d_in[3];
    const float* Wk = (const float*)d_in[4];
    const float* bk = (const float*)d_in[5];
    const float* Wv = (const float*)d_in[6];
    const float* bv = (const float*)d_in[7];
    const float* Wo = (const float*)d_in[8];
    const float* bo = (const float*)d_in[9];
    float* outg  = (float*)d_out;
    float* attng = outg + (size_t)8 * 256 * 128 * 128;   // out first, then attn (fp32)

    __bf16* pk = (__bf16*)d_ws;                          // 4 x 128KB packed weights
    const __bf16* WPq = pk;
    const __bf16* WPk = pk + 65536;
    const __bf16* WPv = pk + 131072;
    const __bf16* WPo = pk + 196608;

    pack_weights<<<dim3(128), dim3(256), 0, stream>>>(Wq, Wk, Wv, Wo, pk);
    wca_fused<<<dim3(2048), dim3(512), 0, stream>>>(
        fa, fb, WPq, bq, WPk, bk, WPv, bv, WPo, bo, outg, attng);
}